// Round 7
// baseline (165.792 us; speedup 1.0000x reference)
//
#include <hip/hip_runtime.h>
#include <hip/hip_bf16.h>
#include <cstdint>

#define NBATCH 512
#define NDIM   2048
#define NHEADS 16
#define NCPH   128

typedef __bf16 bf16x8 __attribute__((ext_vector_type(8)));
typedef float  f32x4  __attribute__((ext_vector_type(4)));

__device__ __forceinline__ unsigned short f2bf(float f) {
    uint32_t u = __builtin_bit_cast(uint32_t, f);
    u += 0x7FFFu + ((u >> 16) & 1u);   // round-to-nearest-even
    return (unsigned short)(u >> 16);
}

// ---------------- bf16-MFMA GEMM, deep-pipelined reg staging -----------
// C[m,n] = sum_k A[m,k]*B[n,k] (+bias[n]).  All operands reg-staged:
// global loads issued TWO K-steps ahead (two named register sets, no
// runtime indexing), cvt+swizzled ds_write one step ahead, raw s_barrier
// with lgkmcnt(0)-only drain => global loads stay in flight across
// barriers (compiler emits counted vmcnt from register deps, never 0).
// 4 waves (2x2), wave = (BM/2)x(BN/2).
// BNP: v-half blocks (n0>=NDIM) emit per-tile BN sums (s, ss).
template<int BM, int BN, int BK, bool A_BF16, bool BNP>
__global__ __launch_bounds__(256) void gemm_deep(
    const unsigned short* __restrict__ Abf, const float* __restrict__ Af,
    const float* __restrict__ Bf, float* __restrict__ C,
    const float* __restrict__ bias, float* __restrict__ bnpart,
    int M, int N, int K)
{
    constexpr int WM = BM / 2, WN = BN / 2;
    constexpr int MI = WM / 16, NI = WN / 16;
    constexpr int CPR = BK / 8;                 // 8-elem chunks per row
    constexpr int RNA = (BM * BK) / 2048;       // A rounds (8 elems/thread)
    constexpr int RNB = (BN * BK) / 2048;       // B rounds

    __shared__ unsigned short As[2][BM * BK];
    __shared__ unsigned short Bs[2][BN * BK];

    const int tid  = threadIdx.x;
    const int lane = tid & 63;
    const int wid  = tid >> 6;
    const int wr   = wid >> 1;
    const int wc   = wid & 1;
    const int m0   = blockIdx.y * BM;
    const int n0   = blockIdx.x * BN;
    const int fr   = lane & 15;
    const int kq   = lane >> 4;

    f32x4 acc[MI][NI] = {};

    // two staging register sets (named, statically indexed)
    float4 fA0[A_BF16 ? 1 : RNA][2], fA1[A_BF16 ? 1 : RNA][2];
    bf16x8 hA0[A_BF16 ? RNA : 1],    hA1[A_BF16 ? RNA : 1];
    float4 fB0[RNB][2], fB1[RNB][2];

    auto loadA = [&](auto& fa, auto& ha, int k0) {
        if constexpr (A_BF16) {
#pragma unroll
            for (int r = 0; r < RNA; r++) {
                const int e = r * 2048 + tid * 8;
                const int row = e / BK, cb = e % BK;
                ha[r] = *(const bf16x8*)(Abf + (size_t)(m0 + row) * K + k0 + cb);
            }
        } else {
#pragma unroll
            for (int r = 0; r < RNA; r++) {
                const int idx = r * 256 + tid;
                const int row = idx / CPR, cc = idx % CPR;
                const float4* g = (const float4*)(Af + (size_t)(m0 + row) * K
                                                  + k0 + cc * 8);
                fa[r][0] = g[0];
                fa[r][1] = g[1];
            }
        }
    };
    auto loadB = [&](auto& fb, int k0) {
#pragma unroll
        for (int r = 0; r < RNB; r++) {
            const int idx = r * 256 + tid;
            const int row = idx / CPR, cc = idx % CPR;
            const float4* g = (const float4*)(Bf + (size_t)(n0 + row) * K
                                              + k0 + cc * 8);
            fb[r][0] = g[0];
            fb[r][1] = g[1];
        }
    };
    auto writeA = [&](int bs, auto& fa, auto& ha) {
        if constexpr (A_BF16) {
#pragma unroll
            for (int r = 0; r < RNA; r++) {
                const int e = r * 2048 + tid * 8;
                const int row = e / BK, cc = (e % BK) >> 3;
                *(bf16x8*)&As[bs][row * BK + ((cc ^ (row & 7)) << 3)] = ha[r];
            }
        } else {
#pragma unroll
            for (int r = 0; r < RNA; r++) {
                const int idx = r * 256 + tid;
                const int row = idx / CPR, cc = idx % CPR;
                bf16x8 v;
                v[0] = (__bf16)fa[r][0].x; v[1] = (__bf16)fa[r][0].y;
                v[2] = (__bf16)fa[r][0].z; v[3] = (__bf16)fa[r][0].w;
                v[4] = (__bf16)fa[r][1].x; v[5] = (__bf16)fa[r][1].y;
                v[6] = (__bf16)fa[r][1].z; v[7] = (__bf16)fa[r][1].w;
                *(bf16x8*)&As[bs][row * BK + ((cc ^ (row & 7)) << 3)] = v;
            }
        }
    };
    auto writeB = [&](int bs, auto& fb) {
#pragma unroll
        for (int r = 0; r < RNB; r++) {
            const int idx = r * 256 + tid;
            const int row = idx / CPR, cc = idx % CPR;
            bf16x8 v;
            v[0] = (__bf16)fb[r][0].x; v[1] = (__bf16)fb[r][0].y;
            v[2] = (__bf16)fb[r][0].z; v[3] = (__bf16)fb[r][0].w;
            v[4] = (__bf16)fb[r][1].x; v[5] = (__bf16)fb[r][1].y;
            v[6] = (__bf16)fb[r][1].z; v[7] = (__bf16)fb[r][1].w;
            *(bf16x8*)&Bs[bs][row * BK + ((cc ^ (row & 7)) << 3)] = v;
        }
    };
    auto compute = [&](int bs) {
#pragma unroll
        for (int kh = 0; kh < BK / 32; kh++) {
            const int kchunk = kh * 4 + kq;
            bf16x8 af[MI], bfv[NI];
#pragma unroll
            for (int i = 0; i < MI; i++) {
                const int row = wr * WM + i * 16 + fr;
                af[i] = *(const bf16x8*)&As[bs][row * BK
                        + ((kchunk ^ (row & 7)) << 3)];
            }
#pragma unroll
            for (int j = 0; j < NI; j++) {
                const int row = wc * WN + j * 16 + fr;
                bfv[j] = *(const bf16x8*)&Bs[bs][row * BK
                         + ((kchunk ^ (row & 7)) << 3)];
            }
#pragma unroll
            for (int i = 0; i < MI; i++)
#pragma unroll
                for (int j = 0; j < NI; j++)
                    acc[i][j] = __builtin_amdgcn_mfma_f32_16x16x32_bf16(
                        af[i], bfv[j], acc[i][j], 0, 0, 0);
        }
    };
    auto barrier = [&]() {
        asm volatile("s_waitcnt lgkmcnt(0)" ::: "memory");
        __builtin_amdgcn_s_barrier();
        __builtin_amdgcn_sched_barrier(0);
    };

    // prologue: tiles 0,1 in flight; buf0 <- tile0
    loadA(fA0, hA0, 0);
    loadB(fB0, 0);
    loadA(fA1, hA1, BK);
    loadB(fB1, BK);
    writeA(0, fA0, hA0);     // compiler: counted vmcnt (set1 outstanding)
    writeB(0, fB0);
    barrier();

    const int NT = K / BK;   // even
    for (int t = 0; t < NT; t += 2) {
        if (t + 2 < NT) { loadA(fA0, hA0, (t + 2) * BK); loadB(fB0, (t + 2) * BK); }
        compute(0);                        // tile t
        writeA(1, fA1, hA1);               // tile t+1 -> buf1
        writeB(1, fB1);
        barrier();
        if (t + 3 < NT) { loadA(fA1, hA1, (t + 3) * BK); loadB(fB1, (t + 3) * BK); }
        compute(1);                        // tile t+1
        if (t + 2 < NT) {
            writeA(0, fA0, hA0);           // tile t+2 -> buf0
            writeB(0, fB0);
            barrier();
        }
    }

    const int row0 = m0 + wr * WM + (kq << 2);
    const int col0 = n0 + wc * WN + fr;
#pragma unroll
    for (int j = 0; j < NI; j++) {
        const int cc = col0 + j * 16;
        const float badd = bias ? bias[cc] : 0.0f;
#pragma unroll
        for (int i = 0; i < MI; i++)
#pragma unroll
            for (int r = 0; r < 4; r++)
                C[(size_t)(row0 + i * 16 + r) * N + cc] = acc[i][j][r] + badd;
    }

    if (BNP && n0 >= NDIM) {
        float s = 0.f, ss = 0.f;
#pragma unroll
        for (int i = 0; i < MI; i++)
#pragma unroll
            for (int j = 0; j < NI; j++)
#pragma unroll
                for (int r = 0; r < 4; r++) {
                    const float v = acc[i][j][r];
                    s += v;
                    ss = fmaf(v, v, ss);
                }
#pragma unroll
        for (int off = 32; off; off >>= 1) {
            s  += __shfl_down(s, off);
            ss += __shfl_down(ss, off);
        }
        __shared__ float rs[4], rss[4];
        if (lane == 0) { rs[wid] = s; rss[wid] = ss; }
        __syncthreads();
        if (tid == 0)
            ((float2*)bnpart)[((n0 - NDIM) >> 6) * 8 + (m0 >> 6)] =
                make_float2(rs[0] + rs[1] + rs[2] + rs[3],
                            rss[0] + rss[1] + rss[2] + rss[3]);
    }
}

// ---------------- fused BN-final + outer-product + softmax + PV --------
// Single-pass no-max softmax (|logit| <~ 30 << 88).  4 threads per row:
// bias regs 32 VGPR -> higher occupancy; all 8 float4 in flight upfront.
// block = half a (b,h): 64 rows x 128 cols;  grid 16384.
__global__ __launch_bounds__(256) void attn_k(
    const float* __restrict__ qv, const float* __restrict__ kparam,
    const float* __restrict__ bias, const float* __restrict__ temperature,
    const float* __restrict__ bnpart, const float* __restrict__ gamma,
    const float* __restrict__ beta, unsigned short* __restrict__ aout)
{
    const int bh2 = blockIdx.x;
    const int bh  = bh2 >> 1, rh = bh2 & 1;
    const int b   = bh >> 4,  h  = bh & 15;
    const int tid = threadIdx.x;

    __shared__ float ks[NCPH], vsr[NCPH], s2sh[2];
    if (tid < 32)
        ((float4*)ks)[tid] =
            ((const float4*)(kparam + (size_t)b * NDIM + h * NCPH))[tid];
    else if (tid < 64)
        ((float4*)vsr)[tid - 32] =
            ((const float4*)(qv + (size_t)b * (2 * NDIM) + NDIM + h * NCPH))[tid - 32];

    if (tid < 16) {   // BN finalize: 16 partials for this head
        float2 p = ((const float2*)bnpart)[(h * 2 + (tid >> 3)) * 8 + (tid & 7)];
        float s = p.x, ss = p.y;
#pragma unroll
        for (int off = 8; off; off >>= 1) {
            s  += __shfl_xor(s, off);
            ss += __shfl_xor(ss, off);
        }
        if (tid == 0) {
            const float inv = 1.0f / (NBATCH * NCPH);
            float mean = s * inv;
            float var  = ss * inv - mean * mean;
            float scl  = gamma[h] * rsqrtf(var + 1e-5f);
            s2sh[0] = scl;
            s2sh[1] = beta[h] - mean * scl;
        }
    }

    const int c  = rh * 64 + (tid >> 2);   // row within head
    const int q4 = tid & 3;                // quarter of the 128 cols
    const float qc   = qv[(size_t)b * (2 * NDIM) + h * NCPH + c];
    const float temp = temperature[h];

    // all 32 bias values in flight before any dependent compute
    const float4* bp = (const float4*)(bias + ((size_t)bh << 14)
                                       + (size_t)c * NCPH + q4 * 32);
    float4 l4[8];
#pragma unroll
    for (int j = 0; j < 8; j++) l4[j] = bp[j];

    __syncthreads();
    const float scl = s2sh[0], shf = s2sh[1];
    const float4* kk4 = (const float4*)(ks  + q4 * 32);
    const float4* vv4 = (const float4*)(vsr + q4 * 32);

    float s0 = 0.f, s1 = 0.f, o0 = 0.f, o1 = 0.f;
#pragma unroll
    for (int j = 0; j < 8; j++) {
        const float4 bb = l4[j];
        const float4 kx = kk4[j];
        const float4 vx = vv4[j];
        float px = __expf(fmaf(qc, kx.x, bb.x) * temp);
        float py = __expf(fmaf(qc, kx.y, bb.y) * temp);
        float pz = __expf(fmaf(qc, kx.z, bb.z) * temp);
        float pw = __expf(fmaf(qc, kx.w, bb.w) * temp);
        s0 += px; s1 += py; s0 += pz; s1 += pw;
        o0 = fmaf(px, vx.x, o0);
        o1 = fmaf(py, vx.y, o1);
        o0 = fmaf(pz, vx.z, o0);
        o1 = fmaf(pw, vx.w, o1);
    }
    float s = s0 + s1, o = o0 + o1;
    s += __shfl_xor(s, 1);
    o += __shfl_xor(o, 1);
    s += __shfl_xor(s, 2);
    o += __shfl_xor(o, 2);

    if (q4 == 0)
        aout[(size_t)b * NDIM + h * NCPH + c] = f2bf(fmaf(scl, o / s, shf));
}

// ------------------------------ launch ---------------------------------
extern "C" void kernel_launch(void* const* d_in, const int* in_sizes, int n_in,
                              void* d_out, int out_size, void* d_ws, size_t ws_size,
                              hipStream_t stream)
{
    const float* x      = (const float*)d_in[0];
    const float* Wqv    = (const float*)d_in[1];
    const float* temp   = (const float*)d_in[2];
    const float* kparam = (const float*)d_in[3];
    const float* bias   = (const float*)d_in[4];
    const float* gamma  = (const float*)d_in[5];
    const float* beta   = (const float*)d_in[6];
    const float* Wout   = (const float*)d_in[7];
    const float* bout   = (const float*)d_in[8];
    float* out = (float*)d_out;

    char* ws = (char*)d_ws;
    float*          qv     = (float*)(ws);                      // 8 MiB
    unsigned short* ao_bf  = (unsigned short*)(ws + 8388608);   // 2 MiB
    float*          bnpart = (float*)(ws + 10485760);           // 2 KiB

    // qv = x @ W_qv^T : M=512, N=4096, K=2048 (512 blocks; in-stage cvt)
    gemm_deep<64, 64, 64, false, true><<<dim3(64, 8), 256, 0, stream>>>(
        nullptr, x, Wqv, qv, nullptr, bnpart, NBATCH, 2 * NDIM, NDIM);

    attn_k<<<2 * NBATCH * NHEADS, 256, 0, stream>>>(
        qv, kparam, bias, temp, bnpart, gamma, beta, ao_bf);

    // out = attn_out @ W_out^T + b_out : M=512, N=2048, K=2048 (512 blocks)
    gemm_deep<64, 32, 64, true, false><<<dim3(64, 8), 256, 0, stream>>>(
        ao_bf, nullptr, Wout, out, bout, nullptr, NBATCH, NDIM, NDIM);
}